// Round 1
// 4383.530 us; speedup vs baseline: 1.2062x; 1.2062x over previous
//
#include <hip/hip_runtime.h>
#include <math.h>

#define BB 32
#define VV 3
#define SS 106
#define TIN 30
#define WID 32
#define MOD 16
#define NL 6
#define NPIX (SS*SS)
#define KX 32
#define WLAYER (WID*WID*VV*VV*MOD*MOD)
#define ROWF (SS*WID)          // 3392 floats per (b,v,x) row of h
#define AESZ 1024              // floats per (b,v,x) slice of A/G
#define TWO_PI_F 6.2831853071795864769f

// table layout in tabs (13312 floats):
// [0,1792)      Tc[16][112]   = 2/NPIX * cos(2pi*(y*ky%106)/106), 0 for y>=106
// [1792,3584)   Ts[16][112]   = 2/NPIX * sin(...)
// [3584,7168)   Tf[112][32]   = [y][2ky]=cos, [y][2ky+1]=-sin
// [7168,13312)  cwT[6][32][32] = convw[L][j][c] transposed -> [L][c][j]
__global__ void k_init(const float* __restrict__ convw, float* __restrict__ tabs) {
    int i = blockIdx.x*256 + threadIdx.x;
    const float n2 = 2.0f / (float)NPIX;
    if (i < 1792) {
        int ky = i/112, y = i%112;
        float v = 0.f;
        if (y < SS) { int m = (y*ky)%SS; v = n2 * cosf(TWO_PI_F*(float)m/(float)SS); }
        tabs[i] = v;
    } else if (i < 3584) {
        int t = i - 1792; int ky = t/112, y = t%112;
        float v = 0.f;
        if (y < SS) { int m = (y*ky)%SS; v = n2 * sinf(TWO_PI_F*(float)m/(float)SS); }
        tabs[i] = v;
    } else if (i < 7168) {
        int t = i - 3584; int y = t>>5, kk = t&31; int ky = kk>>1;
        float v = 0.f;
        if (y < SS) {
            int m = (y*ky)%SS; float ang = TWO_PI_F*(float)m/(float)SS;
            v = (kk&1) ? -sinf(ang) : cosf(ang);
        }
        tabs[i] = v;
    } else if (i < 13312) {
        int t = i - 7168; int L = t>>10, r2 = t&1023; int c = r2>>5, j = r2&31;
        tabs[i] = convw[L*1024 + j*32 + c];
    }
}

// ---------------- fc0 (lift) + forward y-DFT ----------------
// grid B*V*S (b,v,xr). h channel-last: h[blk*3392 + y*32 + c]
// A[blk*1024 + c*32 + ky*2 + ri]
__global__ void k_fc0A(const float* __restrict__ xin, const float* __restrict__ gridx,
                       const float* __restrict__ gridy, const float* __restrict__ fw,
                       const float* __restrict__ fb,
                       float* __restrict__ h, float* __restrict__ A) {
    int blk = blockIdx.x;
    int xr = blk % SS; int bv = blk / SS; int v = bv % VV; int b = bv / VV;
    __shared__ float sx[SS*31];     // [y][30] pad 31, 13.1 KB
    __shared__ float sw[32*WID];    // 4 KB
    __shared__ float sE[SS*33];     // 13.7 KB
    __shared__ float sb[WID];
    __shared__ float2 tw[112];      // e^{2pi i m/106}
    const float* xrow = xin + ((size_t)(b*VV + v)*SS + xr) * (size_t)(SS*TIN);
    for (int i = threadIdx.x; i < SS*TIN; i += 256) sx[(i/30)*31 + (i%30)] = xrow[i];
    for (int i = threadIdx.x; i < 32*WID; i += 256) sw[i] = fw[i];
    if (threadIdx.x < WID) sb[threadIdx.x] = fb[threadIdx.x];
    if (threadIdx.x < SS) {
        float ang = TWO_PI_F * (float)threadIdx.x / (float)SS;
        tw[threadIdx.x] = make_float2(cosf(ang), sinf(ang));
    }
    __syncthreads();
    float gx = gridx[xr];
    int y = threadIdx.x & 127;
    int wg = threadIdx.x >> 7;
    if (y < SS) {
        float gy = gridy[y];
        for (int w = wg; w < WID; w += 2) {
            float acc = sb[w] + gx * sw[30*WID + w] + gy * sw[31*WID + w];
            #pragma unroll
            for (int t = 0; t < TIN; t++) acc += sx[y*31 + t] * sw[t*WID + w];
            sE[y*33 + w] = acc;
        }
    }
    __syncthreads();
    float* hbase = h + (size_t)blk * ROWF;
    for (int i = threadIdx.x*4; i < ROWF; i += 1024)
        *(float4*)(hbase + i) = *(const float4*)&sE[i + (i>>5)];
    // forward y-DFT
    {
        int j = threadIdx.x & 31;
        int kyg = threadIdx.x >> 5;   // 0..7
        int ky0 = kyg*2;
        float r0=0.f,i0=0.f,r1=0.f,i1=0.f;
        int m0 = 0, m1 = 0;
        for (int yy = 0; yy < SS; yy++) {
            float hv = sE[yy*33 + j];
            float2 t0 = tw[m0];
            float2 t1 = tw[m1];
            r0 += hv*t0.x; i0 -= hv*t0.y;
            r1 += hv*t1.x; i1 -= hv*t1.y;
            m0 += ky0;   if (m0 >= SS) m0 -= SS;
            m1 += ky0+1; if (m1 >= SS) m1 -= SS;
        }
        *(float4*)&sx[j*32 + kyg*4] = make_float4(r0, i0, r1, i1);
    }
    __syncthreads();
    float* Abase = A + (size_t)blk * AESZ;
    for (int i = threadIdx.x*4; i < AESZ; i += 1024)
        *(float4*)(Abase + i) = *(const float4*)&sx[i];
}

// ---------------- stage B: forward x-DFT ----------------
// grid 768: blk -> cg(8), v(3), b(32). block 128. hf[b][kx][ky][ip][2]
__global__ void k_B(const float* __restrict__ A, float* __restrict__ hf) {
    int blk = blockIdx.x;
    int cg = blk & 7; int v = (blk >> 3) % 3; int b = blk / 24;
    __shared__ float stx[SS*64];    // [x][k][2] 27.1 KB
    __shared__ float sAx[8*128];    // 8 x-rows of [c4][ky][2], 4 KB
    __shared__ float2 tw[112];
    if (threadIdx.x < SS) {
        float ang = TWO_PI_F * (float)threadIdx.x / (float)SS;
        tw[threadIdx.x] = make_float2(cosf(ang), sinf(ang));
    }
    __syncthreads();
    for (int i = threadIdx.x; i < SS*KX; i += 128) {
        int x = i >> 5, k = i & 31;
        int kxv = (k < 16) ? k : (k + 74);
        int m = (x * kxv) % SS;
        float2 t = tw[m];
        stx[i*2] = t.x; stx[i*2+1] = t.y;
    }
    int kxh = threadIdx.x >> 6;        // 0..1
    int ky  = (threadIdx.x >> 2) & 15;
    int c   = threadIdx.x & 3;
    float ar[16], ai[16];
    #pragma unroll
    for (int k = 0; k < 16; k++) { ar[k]=0.f; ai[k]=0.f; }
    const float* Abase = A + ((size_t)(b*VV + v)*SS)*AESZ + cg*128;
    for (int xb = 0; xb < SS; xb += 8) {
        int nx = (SS - xb < 8) ? (SS - xb) : 8;
        __syncthreads();
        for (int i = threadIdx.x; i < nx*32; i += 128) {
            int xl = i >> 5, r = i & 31;
            ((float4*)sAx)[xl*32 + r] = *(const float4*)&Abase[(size_t)(xb+xl)*AESZ + r*4];
        }
        __syncthreads();
        for (int xl = 0; xl < nx; xl++) {
            int x = xb + xl;
            float2 a = *(const float2*)&sAx[xl*128 + c*32 + ky*2];
            #pragma unroll
            for (int kxl = 0; kxl < 16; kxl++) {
                int kx2 = kxh*16 + kxl;
                float tc = stx[x*64 + kx2*2], ts = stx[x*64 + kx2*2 + 1];
                ar[kxl] += a.x*tc + a.y*ts;
                ai[kxl] += a.y*tc - a.x*ts;
            }
        }
    }
    int ip = (cg*4 + c)*3 + v;
    #pragma unroll
    for (int kxl = 0; kxl < 16; kxl++) {
        int kx = kxh*16 + kxl;
        size_t idx = ((((size_t)b*KX + kx)*MOD + ky)*96 + ip)*2;
        hf[idx] = ar[kxl]; hf[idx+1] = ai[kxl];
    }
}

// ---------------- stage C: mode mixing ----------------
// grid (kxi=32, jqc=6, bg=2). oft[b][jq][kx][ky][2]
__global__ void k_C(const float* __restrict__ hf,
                    const float* __restrict__ w1r, const float* __restrict__ w1i,
                    const float* __restrict__ w2r, const float* __restrict__ w2i,
                    float* __restrict__ oft) {
    int kxi = blockIdx.x;
    int jqc = blockIdx.y;
    int bg  = blockIdx.z;
    int ky  = threadIdx.x & 15;
    int jql = threadIdx.x >> 4;
    int jq  = jqc*16 + jql;
    int j = jq / 3, q = jq % 3;
    const float* wr; const float* wi; int kxm = kxi & 15;
    if (kxi < 16) { wr = w1r; wi = w1i; }
    else          { wr = w2r; wi = w2i; }
    float accr[16], acci[16];
    #pragma unroll
    for (int t = 0; t < 16; t++) { accr[t]=0.f; acci[t]=0.f; }
    __shared__ float2 shf2[8*16*17];   // [ipl][bl][ky pad17]
    int sbl = threadIdx.x & 15;
    int sky = threadIdx.x >> 4;
    for (int ip0 = 0; ip0 < 96; ip0 += 8) {
        __syncthreads();
        {
            const float* gsrc = hf + ((((size_t)(bg*16+sbl)*KX + kxi)*MOD + sky)*96 + ip0)*2;
            #pragma unroll
            for (int u = 0; u < 4; u++) {
                float4 f = *(const float4*)(gsrc + u*4);
                shf2[((u*2  )*16 + sbl)*17 + sky] = make_float2(f.x, f.y);
                shf2[((u*2+1)*16 + sbl)*17 + sky] = make_float2(f.z, f.w);
            }
        }
        __syncthreads();
        #pragma unroll
        for (int ipl = 0; ipl < 8; ipl++) {
            int ip = ip0 + ipl;
            int iw = ip / 3, p = ip % 3;
            size_t widx = (((((size_t)iw*WID + j)*VV + p)*VV + q)*MOD + kxm)*MOD + ky;
            float wrv = wr[widx];
            float wiv = wi[widx];
            #pragma unroll
            for (int bl = 0; bl < 16; bl++) {
                float2 hv = shf2[(ipl*16 + bl)*17 + ky];
                accr[bl] += hv.x * wrv - hv.y * wiv;
                acci[bl] += hv.x * wiv + hv.y * wrv;
            }
        }
    }
    #pragma unroll
    for (int bl = 0; bl < 16; bl++) {
        int b = bg*16 + bl;
        float2* out = (float2*)(oft + ((((size_t)b*96 + jq)*KX + kxi)*MOD + ky)*2);
        *out = make_float2(accr[bl], acci[bl]);
    }
}

// ---------------- stage D: inverse x-DFT ----------------
// grid 3072 (b*96+jq). G[((b*3+v)*106+x)*1024 + j*32 + ky*2]
__global__ void k_D(const float* __restrict__ oft, float* __restrict__ G) {
    int ch = blockIdx.x;
    int b = ch / 96; int jq = ch % 96; int j = jq / 3; int v = jq % 3;
    __shared__ float so[KX*MOD*2];   // 4 KB
    __shared__ float str[KX*107];    // 13.7 KB
    __shared__ float sti[KX*107];    // 13.7 KB
    __shared__ float2 tw[112];
    if (threadIdx.x < SS) {
        float ang = TWO_PI_F * (float)threadIdx.x / (float)SS;
        tw[threadIdx.x] = make_float2(cosf(ang), sinf(ang));
    }
    const float* src = oft + (size_t)ch * (KX*MOD*2);
    for (int i = threadIdx.x*4; i < KX*MOD*2; i += 1024)
        *(float4*)&so[i] = *(const float4*)&src[i];
    __syncthreads();
    for (int i = threadIdx.x; i < KX*SS; i += 256) {
        int k = i / SS, x = i % SS;
        int kxv = (k < 16) ? k : (k + 74);
        int m = (x * kxv) % SS;
        float2 t = tw[m];
        str[k*107 + x] = t.x;
        sti[k*107 + x] = t.y;
    }
    __syncthreads();
    int ky = threadIdx.x & 15;
    int xg = threadIdx.x >> 4;
    float* Gb = G + ((size_t)(b*VV + v)*SS)*AESZ + j*32 + ky*2;
    for (int xx = xg; xx < SS; xx += 16) {
        float gr = 0.f, gi = 0.f;
        #pragma unroll
        for (int k = 0; k < KX; k++) {
            float2 o = *(const float2*)&so[(k*MOD + ky)*2];
            float tc = str[k*107 + xx], ts = sti[k*107 + xx];
            gr += o.x*tc - o.y*ts;
            gi += o.x*ts + o.y*tc;
        }
        *(float2*)(Gb + (size_t)xx*AESZ) = make_float2(gr, gi);
    }
}

// ---------------- stage E v2: register-tiled iDFT_y + conv (+gelu) + fwd y-DFT ----------------
// grid B*V*S, 256 threads. LDS 38.3 KB -> 4 blocks/CU.
// Phase 1: 224 threads, 4y x 4j register tiles; K-loops over ky (15) and c (32),
//          all operands via b64/b128 broadcast-friendly LDS reads.
// Phase 2: 256 threads, split-K (2 y-halves) 2kk x 4j tiles + LDS reduction.
__global__ __launch_bounds__(256, 4) void k_E(
    float* __restrict__ G, const float* __restrict__ hold,
    const float* __restrict__ cwT, const float* __restrict__ cb,
    const float* __restrict__ tabs, float* __restrict__ hnew,
    int do_gelu, int writeA)
{
    int blk = blockIdx.x;
    int tid = threadIdx.x;
    __shared__ __align__(16) float lds[9568];     // 38272 B
    float* sGp = lds;            // [32][38]  G padded (phase 1)
    float* sHt = lds + 1216;     // [32][116] hold transposed (phase 1)
    float* sTc = lds + 4928;     // [16][112] + sTs contiguous (phase 1)
    float* sTs = lds + 6720;
    float* scw = lds + 8512;     // [32][32] cwT[c][j] (phase 1)
    float* scb = lds + 9536;     // [32]
    float* sE  = lds;            // [112][40] (phase 2, aliases sGp/sHt)
    float* sTf = lds + 4928;     // [112][32] (phase 2, aliases sTc/sTs)
    float* sRd = lds + 8512;     // [1024]    (phase 2, aliases scw)

    // ---- stage phase-1 operands ----
    const float* Gs = G + (size_t)blk * AESZ;
    for (int i = tid*2; i < AESZ; i += 512) {
        float2 g = *(const float2*)&Gs[i];
        *(float2*)&sGp[(i>>5)*38 + (i&31)] = g;
    }
    const float4* h4 = (const float4*)(hold + (size_t)blk * ROWF);
    for (int i4 = tid; i4 < ROWF/4; i4 += 256) {
        float4 f = h4[i4];
        int y = i4 >> 3, c0 = (i4 & 7) * 4;
        sHt[(c0  )*116 + y] = f.x;
        sHt[(c0+1)*116 + y] = f.y;
        sHt[(c0+2)*116 + y] = f.z;
        sHt[(c0+3)*116 + y] = f.w;
    }
    for (int i = tid*4; i < 3584; i += 1024)
        *(float4*)&sTc[i] = *(const float4*)&tabs[i];           // Tc+Ts
    *(float4*)&scw[tid*4] = *(const float4*)&cwT[tid*4];        // 1024 exactly
    if (tid < 32) scb[tid] = cb[tid];
    __syncthreads();

    // ---- phase 1: E[y][j] = norm*Gdc + cb + sum_ky(Gr*Tc - Gi*Ts) + sum_c h*cw ----
    float acc[4][4];
    int yt = tid >> 3, jt = tid & 7;       // yt 0..27 (4y), jt 0..7 (4j)
    if (tid < 224) {
        const float nrm = 1.0f/(float)NPIX;
        float4 cbv = *(const float4*)&scb[jt*4];
        #pragma unroll
        for (int jj = 0; jj < 4; jj++) {
            float dc = sGp[(jt*4+jj)*38] * nrm + ((const float*)&cbv)[jj];
            acc[0][jj]=dc; acc[1][jj]=dc; acc[2][jj]=dc; acc[3][jj]=dc;
        }
        #pragma unroll
        for (int ky = 1; ky < MOD; ky++) {
            float4 tc = *(const float4*)&sTc[ky*112 + yt*4];
            float4 ts = *(const float4*)&sTs[ky*112 + yt*4];
            float2 g0 = *(const float2*)&sGp[(jt*4  )*38 + 2*ky];
            float2 g1 = *(const float2*)&sGp[(jt*4+1)*38 + 2*ky];
            float2 g2 = *(const float2*)&sGp[(jt*4+2)*38 + 2*ky];
            float2 g3 = *(const float2*)&sGp[(jt*4+3)*38 + 2*ky];
            #pragma unroll
            for (int yy = 0; yy < 4; yy++) {
                float tcv = ((const float*)&tc)[yy];
                float tsv = ((const float*)&ts)[yy];
                acc[yy][0] += g0.x*tcv - g0.y*tsv;
                acc[yy][1] += g1.x*tcv - g1.y*tsv;
                acc[yy][2] += g2.x*tcv - g2.y*tsv;
                acc[yy][3] += g3.x*tcv - g3.y*tsv;
            }
        }
        #pragma unroll
        for (int c = 0; c < 32; c++) {
            float4 hv = *(const float4*)&sHt[c*116 + yt*4];
            float4 wv = *(const float4*)&scw[c*32 + jt*4];
            #pragma unroll
            for (int yy = 0; yy < 4; yy++) {
                float hvy = ((const float*)&hv)[yy];
                acc[yy][0] += hvy * wv.x;
                acc[yy][1] += hvy * wv.y;
                acc[yy][2] += hvy * wv.z;
                acc[yy][3] += hvy * wv.w;
            }
        }
        if (do_gelu) {
            #pragma unroll
            for (int yy = 0; yy < 4; yy++)
            #pragma unroll
            for (int jj = 0; jj < 4; jj++) {
                float a = acc[yy][jj];
                acc[yy][jj] = 0.5f*a*(1.f + erff(a*0.70710678118654752440f));
            }
        }
    }
    __syncthreads();   // all phase-1 reads done; regions may be overwritten

    if (tid < 224) {
        #pragma unroll
        for (int yy = 0; yy < 4; yy++)
            *(float4*)&sE[(yt*4+yy)*40 + jt*4] =
                make_float4(acc[yy][0], acc[yy][1], acc[yy][2], acc[yy][3]);
    }
    if (writeA) {
        for (int i = tid*4; i < 3584; i += 1024)
            *(float4*)&sTf[i] = *(const float4*)&tabs[3584 + i];
    }
    __syncthreads();

    // ---- write hnew (coalesced) ----
    float* hb = hnew + (size_t)blk * ROWF;
    for (int i = tid*4; i < ROWF; i += 1024)
        *(float4*)(hb + i) = *(const float4*)&sE[(i>>5)*40 + (i&31)];

    // ---- phase 2: A[j][kk] = sum_y E[y][j] * Tf[y][kk] (split over 2 y-halves) ----
    if (writeA) {
        int hh = tid >> 7, r = tid & 127;
        int kt = r & 15, jt2 = r >> 4;     // kk pair 2kt, j tile 4*jt2
        float a0[4] = {0.f,0.f,0.f,0.f}, a1[4] = {0.f,0.f,0.f,0.f};
        int y = hh*53;
        for (int i = 0; i < 53; i++, y++) {
            float2 tf = *(const float2*)&sTf[y*32 + kt*2];
            float4 e  = *(const float4*)&sE[y*40 + jt2*4];
            a0[0] += tf.x*e.x; a0[1] += tf.x*e.y; a0[2] += tf.x*e.z; a0[3] += tf.x*e.w;
            a1[0] += tf.y*e.x; a1[1] += tf.y*e.y; a1[2] += tf.y*e.z; a1[3] += tf.y*e.w;
        }
        if (hh) {
            *(float4*)&sRd[r*8]   = make_float4(a0[0],a0[1],a0[2],a0[3]);
            *(float4*)&sRd[r*8+4] = make_float4(a1[0],a1[1],a1[2],a1[3]);
        }
        __syncthreads();
        if (!hh) {
            float4 b0 = *(const float4*)&sRd[r*8];
            float4 b1 = *(const float4*)&sRd[r*8+4];
            a0[0]+=b0.x; a0[1]+=b0.y; a0[2]+=b0.z; a0[3]+=b0.w;
            a1[0]+=b1.x; a1[1]+=b1.y; a1[2]+=b1.z; a1[3]+=b1.w;
            float* Ab = G + (size_t)blk*AESZ + jt2*128 + kt*2;
            *(float2*)&Ab[0]  = make_float2(a0[0], a1[0]);
            *(float2*)&Ab[32] = make_float2(a0[1], a1[1]);
            *(float2*)&Ab[64] = make_float2(a0[2], a1[2]);
            *(float2*)&Ab[96] = make_float2(a0[3], a1[3]);
        }
    }
}

// ---------------- head: fc1 + gelu + fc2 ----------------
__global__ void k_head(const float* __restrict__ h, const float* __restrict__ fc1w,
                       const float* __restrict__ fc1b, const float* __restrict__ fc2w,
                       const float* __restrict__ fc2b, float* __restrict__ out) {
    int blk = blockIdx.x;
    __shared__ float sh[SS*33];
    __shared__ float sw1[WID*128];
    __shared__ float sb1[128];
    __shared__ float sw2[128];
    __shared__ float spart[128*2];
    const float* hs = h + (size_t)blk * ROWF;
    for (int i = threadIdx.x*4; i < ROWF; i += 1024)
        *(float4*)&sh[i + (i>>5)] = *(const float4*)&hs[i];
    for (int i = threadIdx.x*4; i < WID*128; i += 1024)
        *(float4*)&sw1[i] = *(const float4*)&fc1w[i];
    if (threadIdx.x < 128) { sb1[threadIdx.x] = fc1b[threadIdx.x]; sw2[threadIdx.x] = fc2w[threadIdx.x]; }
    __syncthreads();
    int y = threadIdx.x & 127;
    int kh = threadIdx.x >> 7;
    if (y < SS) {
        float hr[WID];
        #pragma unroll
        for (int c = 0; c < WID; c++) hr[c] = sh[y*33 + c];
        float part = 0.f;
        for (int k = kh*64; k < kh*64 + 64; k++) {
            float s = sb1[k];
            #pragma unroll
            for (int c = 0; c < WID; c++) s += hr[c] * sw1[c*128 + k];
            s = 0.5f * s * (1.f + erff(s * 0.70710678118654752440f));
            part += s * sw2[k];
        }
        spart[y*2 + kh] = part;
    }
    __syncthreads();
    if (kh == 0 && y < SS) {
        out[(size_t)blk*SS + y] = spart[y*2] + spart[y*2+1] + fc2b[0];
    }
}

extern "C" void kernel_launch(void* const* d_in, const int* in_sizes, int n_in,
                              void* d_out, int out_size, void* d_ws, size_t ws_size,
                              hipStream_t stream) {
    const float* xin   = (const float*)d_in[0];
    const float* gridx = (const float*)d_in[1];
    const float* gridy = (const float*)d_in[2];
    const float* fc0w  = (const float*)d_in[3];
    const float* fc0b  = (const float*)d_in[4];
    const float* w1r   = (const float*)d_in[5];
    const float* w1i   = (const float*)d_in[6];
    const float* w2r   = (const float*)d_in[7];
    const float* w2i   = (const float*)d_in[8];
    const float* convw = (const float*)d_in[9];
    const float* convb = (const float*)d_in[10];
    const float* fc1w  = (const float*)d_in[11];
    const float* fc1b  = (const float*)d_in[12];
    const float* fc2w  = (const float*)d_in[13];
    const float* fc2b  = (const float*)d_in[14];
    float* out = (float*)d_out;

    float* p = (float*)d_ws;
    float* h0   = p; p += (size_t)BB*VV*SS*ROWF;
    float* h1   = p; p += (size_t)BB*VV*SS*ROWF;
    float* AG   = p; p += (size_t)BB*VV*SS*AESZ;     // A aliased with G
    float* hfb  = p; p += (size_t)BB*KX*MOD*96*2;
    float* oftb = p; p += (size_t)BB*96*KX*MOD*2;
    float* tabs = p; p += (size_t)13312;             // twiddle tables + cwT (53 KB)

    k_init<<<52, 256, 0, stream>>>(convw, tabs);
    k_fc0A<<<BB*VV*SS, 256, 0, stream>>>(xin, gridx, gridy, fc0w, fc0b, h0, AG);

    float* hc = h0; float* hn = h1;
    for (int L = 0; L < NL; L++) {
        k_B<<<BB*VV*8, 128, 0, stream>>>(AG, hfb);
        k_C<<<dim3(KX, 6, 2), 256, 0, stream>>>(hfb,
            w1r + (size_t)L*WLAYER, w1i + (size_t)L*WLAYER,
            w2r + (size_t)L*WLAYER, w2i + (size_t)L*WLAYER, oftb);
        k_D<<<BB*96, 256, 0, stream>>>(oftb, AG);
        k_E<<<BB*VV*SS, 256, 0, stream>>>(AG, hc,
            tabs + 7168 + (size_t)L*1024, convb + (size_t)L*WID, tabs, hn,
            (L < 3) ? 1 : 0, (L < NL-1) ? 1 : 0);
        float* tmp = hc; hc = hn; hn = tmp;
    }
    k_head<<<BB*VV*SS, 256, 0, stream>>>(hc, fc1w, fc1b, fc2w, fc2b, out);
}